// Round 1
// baseline (44.803 us; speedup 1.0000x reference)
//
#include <hip/hip_runtime.h>

// TrajLoss: pos = cumsum(pred.reshape(B,T,2), axis=1);
// loss = sum((pos_x - true[:, :T])^2 + (pos_y - true[:, T:])^2)
// B=8192, L=2048, T=1024. traj_du_true (d_in[1]) is unused by the reference.

constexpr int L_DIM = 2048;
constexpr int T_DIM = 1024;          // L/2
constexpr int ROWS_PER_BLOCK = 4;    // one 64-lane wave per row, 256 threads/block
constexpr int PAIRS_PER_LANE = T_DIM / 64;  // 16 (dx,dy) pairs per lane

__global__ __launch_bounds__(256) void traj_loss_kernel(
    const float* __restrict__ pred,
    const float* __restrict__ pos_true,
    float* __restrict__ out,
    int B)
{
    const int wid  = threadIdx.x >> 6;   // wave id within block
    const int lane = threadIdx.x & 63;
    const int row  = blockIdx.x * ROWS_PER_BLOCK + wid;

    float acc = 0.0f;

    if (row < B) {
        const float* prow = pred     + (size_t)row * L_DIM;
        const float* trow = pos_true + (size_t)row * L_DIM;

        // ---- load 16 (dx,dy) pairs = 32 contiguous floats = 8x float4 ----
        // lane i owns t in [i*16, i*16+16); its floats are [i*32, i*32+32)
        float lpx[PAIRS_PER_LANE];   // local inclusive prefix of dx
        float lpy[PAIRS_PER_LANE];   // local inclusive prefix of dy
        float px = 0.0f, py = 0.0f;
        const float4* p4 = reinterpret_cast<const float4*>(prow) + lane * 8;
#pragma unroll
        for (int j = 0; j < 8; ++j) {
            float4 v = p4[j];            // (dx0,dy0,dx1,dy1)
            px += v.x; py += v.y;
            lpx[2 * j]     = px; lpy[2 * j]     = py;
            px += v.z; py += v.w;
            lpx[2 * j + 1] = px; lpy[2 * j + 1] = py;
        }

        // ---- wave-level inclusive scan of lane totals (px,py) ----
        float sx = px, sy = py;
#pragma unroll
        for (int d = 1; d < 64; d <<= 1) {
            float ux = __shfl_up(sx, d);
            float uy = __shfl_up(sy, d);
            if (lane >= d) { sx += ux; sy += uy; }
        }
        const float ox = sx - px;   // exclusive prefix = running position
        const float oy = sy - py;   // before this lane's chunk

        // ---- squared error vs tx = true[:, :T], ty = true[:, T:] ----
        const float4* tx4 = reinterpret_cast<const float4*>(trow)         + lane * 4;
        const float4* ty4 = reinterpret_cast<const float4*>(trow + T_DIM) + lane * 4;
#pragma unroll
        for (int j = 0; j < 4; ++j) {
            float4 tx = tx4[j];
            float4 ty = ty4[j];
            float ex, ey;
            ex = ox + lpx[4 * j + 0] - tx.x; ey = oy + lpy[4 * j + 0] - ty.x; acc += ex * ex + ey * ey;
            ex = ox + lpx[4 * j + 1] - tx.y; ey = oy + lpy[4 * j + 1] - ty.y; acc += ex * ex + ey * ey;
            ex = ox + lpx[4 * j + 2] - tx.z; ey = oy + lpy[4 * j + 2] - ty.z; acc += ex * ex + ey * ey;
            ex = ox + lpx[4 * j + 3] - tx.w; ey = oy + lpy[4 * j + 3] - ty.w; acc += ex * ex + ey * ey;
        }
    }

    // ---- wave reduce ----
#pragma unroll
    for (int d = 32; d >= 1; d >>= 1) acc += __shfl_xor(acc, d);

    __shared__ float warp_sums[ROWS_PER_BLOCK];
    if (lane == 0) warp_sums[wid] = acc;
    __syncthreads();

    if (threadIdx.x == 0) {
        float s = 0.0f;
#pragma unroll
        for (int w = 0; w < ROWS_PER_BLOCK; ++w) s += warp_sums[w];
        atomicAdd(out, s);
    }
}

extern "C" void kernel_launch(void* const* d_in, const int* in_sizes, int n_in,
                              void* d_out, int out_size, void* d_ws, size_t ws_size,
                              hipStream_t stream) {
    const float* pred     = (const float*)d_in[0];  // traj_pred
    // d_in[1] = traj_du_true — unused by the reference
    const float* pos_true = (const float*)d_in[2];  // traj_pos_true
    float* out = (float*)d_out;

    const int B = in_sizes[0] / L_DIM;

    // d_out is poisoned (0xAA) by the harness and never re-poisoned between
    // timed replays — zero it every call (memset node is graph-capturable).
    hipMemsetAsync(out, 0, sizeof(float), stream);

    const int grid = (B + ROWS_PER_BLOCK - 1) / ROWS_PER_BLOCK;
    traj_loss_kernel<<<grid, 256, 0, stream>>>(pred, pos_true, out, B);
}